// Round 6
// baseline (384.498 us; speedup 1.0000x reference)
//
#include <hip/hip_runtime.h>
#include <hip/hip_bf16.h>

#define TT 2048
#define HD 1024
#define NE 8
#define ID 2048

typedef short bf16x8 __attribute__((ext_vector_type(8)));
typedef float f32x4 __attribute__((ext_vector_type(4)));

__device__ __forceinline__ unsigned f2bf(float f){
  unsigned u = __float_as_uint(f);
  return (u + 0x7FFFu + ((u >> 16) & 1u)) >> 16;  // RNE
}
__device__ __forceinline__ float gelu_t(float x){
  float x3 = x * x * x;
  return 0.5f * x * (1.f + tanhf(0.7978845608028654f * (x + 0.044715f * x3)));
}

// async global->LDS, 16B per lane. LDS dest = wave-uniform base + lane*16;
// global source address is PER-LANE (swizzle lives on the source side).
typedef const __attribute__((address_space(1))) unsigned int as1_uint;
typedef __attribute__((address_space(3))) unsigned int as3_uint;
__device__ __forceinline__ void gll16(const unsigned short* g, unsigned short* l) {
  __builtin_amdgcn_global_load_lds((as1_uint*)g, (as3_uint*)l, 16, 0, 0);
}

// ---------------- Router ----------------
__global__ __launch_bounds__(64) void router_kernel(
    const float* __restrict__ x, const float* __restrict__ gw,
    int* __restrict__ counts, int* __restrict__ list_ak, float* __restrict__ wlist)
{
  int t = blockIdx.x;
  int lane = threadIdx.x;
  float acc[NE];
  #pragma unroll
  for (int e = 0; e < NE; ++e) acc[e] = 0.f;
  const float* xr = x + (size_t)t * HD;
  #pragma unroll
  for (int j = 0; j < HD / 64; ++j) {
    int h = j * 64 + lane;
    float xv = xr[h];
    float4 g0 = *(const float4*)(gw + (size_t)h * NE);
    float4 g1 = *(const float4*)(gw + (size_t)h * NE + 4);
    acc[0] += xv * g0.x; acc[1] += xv * g0.y;
    acc[2] += xv * g0.z; acc[3] += xv * g0.w;
    acc[4] += xv * g1.x; acc[5] += xv * g1.y;
    acc[6] += xv * g1.z; acc[7] += xv * g1.w;
  }
  #pragma unroll
  for (int e = 0; e < NE; ++e) {
    float v = acc[e];
    #pragma unroll
    for (int off = 32; off > 0; off >>= 1) v += __shfl_xor(v, off, 64);
    acc[e] = v;
  }
  if (lane == 0) {
    float lg[NE];
    #pragma unroll
    for (int e = 0; e < NE; ++e) lg[e] = tanhf(acc[e] * (1.0f / 30.0f));
    int i0 = 0;
    #pragma unroll
    for (int e = 1; e < NE; ++e) if (lg[e] > lg[i0]) i0 = e;
    int i1 = (i0 == 0) ? 1 : 0;
    #pragma unroll
    for (int e = 0; e < NE; ++e) if (e != i0 && lg[e] > lg[i1]) i1 = e;
    float e1 = __expf(lg[i1] - lg[i0]);
    float w0 = 1.f / (1.f + e1);
    float w1 = 1.f - w0;
    int p0 = atomicAdd(counts + i0, 1);
    list_ak[i0 * TT + p0] = t * 2;
    wlist[i0 * TT + p0] = w0;
    int p1 = atomicAdd(counts + i1, 1);
    list_ak[i1 * TT + p1] = t * 2 + 1;
    wlist[i1 * TT + p1] = w1;
  }
}

// ---------------- x fp32 -> bf16 ----------------
__global__ void xcvt_kernel(const float* __restrict__ x, unsigned short* __restrict__ xb)
{
  int i = blockIdx.x * blockDim.x + threadIdx.x;   // 8 elems each
  const float* p = x + (size_t)i * 8;
  float4 v0 = *(const float4*)p;
  float4 v1 = *(const float4*)(p + 4);
  uint4 o;
  o.x = f2bf(v0.x) | (f2bf(v0.y) << 16);
  o.y = f2bf(v0.z) | (f2bf(v0.w) << 16);
  o.z = f2bf(v1.x) | (f2bf(v1.y) << 16);
  o.w = f2bf(v1.z) | (f2bf(v1.w) << 16);
  *(uint4*)(xb + (size_t)i * 8) = o;
}

// ---------------- weight transpose+convert: in fp32 [R][C] -> out bf16 [C][R]
__global__ __launch_bounds__(256) void tcvt_kernel(
    const float* __restrict__ in, unsigned short* __restrict__ out, int R, int C)
{
  __shared__ float tile[64 * 66];
  int e = blockIdx.z;
  const float* inp = in + (size_t)e * R * C;
  unsigned short* outp = out + (size_t)e * R * C;
  int r0 = blockIdx.y * 64, c0 = blockIdx.x * 64;
  int tid = threadIdx.x;
  int lr = tid >> 4, lc = (tid & 15) * 4;
  #pragma unroll
  for (int i = 0; i < 4; ++i) {
    float4 v = *(const float4*)(inp + (size_t)(r0 + i * 16 + lr) * C + c0 + lc);
    float* tp = &tile[(i * 16 + lr) * 66 + lc];
    tp[0] = v.x; tp[1] = v.y; tp[2] = v.z; tp[3] = v.w;
  }
  __syncthreads();
  int oc = tid >> 2, os = (tid & 3) * 16;
  unsigned short* op = outp + (size_t)(c0 + oc) * R + r0 + os;
  uint4 o[2];
  unsigned* ow = (unsigned*)o;
  #pragma unroll
  for (int m = 0; m < 8; ++m) {
    float a = tile[(os + 2 * m) * 66 + oc];
    float b = tile[(os + 2 * m + 1) * 66 + oc];
    ow[m] = f2bf(a) | (f2bf(b) << 16);
  }
  *(uint4*)op = o[0];
  *(uint4*)(op + 8) = o[1];
}

#define BK 32
#define BM 128

// LDS: linear [rows][32 k] bf16 (64B rows), staged entirely by global_load_lds
// (per-lane gather on the GLOBAL side). 16B-unit XOR swizzle pre-applied to the
// global source k-chunk: stored unit u of row r holds chunk u^((r>>1)&3); frag
// reads apply the same XOR -> conflict-free (measured 0).
// Round-6: 3-stage pipeline, 2 tiles in flight per wave. R5 showed the
// achieved fabric rate scales with outstanding depth (R2: 8.4 TB/s @ ~4
// domains/CU vs R5: 5.1 TB/s @ 1-tile-deep). At iter t: stage(t+2), then
// vmcnt(N_2tiles) waits only for tile t; loads get TWO iterations of slack
// and per-wave in-flight bytes double.

// ---------------- Fused G+U gathered GEMM, act epilogue ----------------
// 8 waves as 2m x 4n: wave computes 64m x 32n of both G and U.
__global__ __launch_bounds__(512, 4) void gu_gemm(
    const unsigned short* __restrict__ xb,   // [T,H] bf16
    const unsigned short* __restrict__ wgT,  // [E][I][H] bf16 (transposed)
    const unsigned short* __restrict__ wuT,
    unsigned short* __restrict__ act,        // [T*2, I] bf16
    const int* __restrict__ counts, const int* __restrict__ list_ak)
{
  int e = blockIdx.z;
  int nCnt = counts[e];
  int m0 = blockIdx.y * BM;
  if (m0 >= nCnt) return;
  int c0 = blockIdx.x * 128;
  const unsigned short* Wg = wgT + (size_t)e * HD * ID;
  const unsigned short* Wu = wuT + (size_t)e * HD * ID;

  __shared__ __align__(16) unsigned short As[3][BM * BK];    // 24 KB
  __shared__ __align__(16) unsigned short Bg[3][128 * BK];   // 24 KB
  __shared__ __align__(16) unsigned short Bu[3][128 * BK];   // 24 KB

  int tid = threadIdx.x;
  int wave = tid >> 6, lane = tid & 63;      // 8 waves
  int wm = wave >> 2, wnq = wave & 3;        // 2m x 4n
  int q = lane >> 4, l15 = lane & 15;
  int usw = ((lane & 3) ^ ((lane >> 3) & 3)) * 8;  // source k-chunk (shorts)
  int fsw = (q ^ ((l15 >> 1) & 3)) * 8;            // frag-read swizzle

  // staging: wave w covers rows/cols w*16 .. w*16+15 (lane>>2), unit lane&3
  int srow = wave * 16 + (lane >> 2);
  int gpos = m0 + srow; if (gpos >= nCnt) gpos = nCnt - 1;   // clamp, row unused
  const unsigned short* aptr =
      xb + (size_t)(list_ak[e * TT + gpos] >> 1) * HD + usw;
  const unsigned short* bgp = Wg + (size_t)(c0 + srow) * HD + usw;
  const unsigned short* bup = Wu + (size_t)(c0 + srow) * HD + usw;
  int so = wave * 512;   // shorts: wave-uniform LDS base (16 rows * 32)

  // 3 glls per wave per tile
  auto stage = [&](int k0, int b) {
    gll16(aptr + k0, &As[b][so]);
    gll16(bgp + k0,  &Bg[b][so]);
    gll16(bup + k0,  &Bu[b][so]);
  };

  f32x4 accg[4][2], accu[4][2];
  f32x4 zed = {0.f, 0.f, 0.f, 0.f};
  #pragma unroll
  for (int i = 0; i < 4; ++i)
    #pragma unroll
    for (int j = 0; j < 2; ++j) { accg[i][j] = zed; accu[i][j] = zed; }

  stage(0, 0);
  stage(BK, 1);

  int cur = 0;
  for (int k0 = 0; k0 < HD; k0 += BK) {
    int n2 = k0 + 2 * BK;
    if (n2 < HD) {
      int b2 = cur + 2; if (b2 >= 3) b2 -= 3;
      stage(n2, b2);
      asm volatile("s_waitcnt vmcnt(6)" ::: "memory");  // t+1,t+2 in flight
    } else if (k0 + BK < HD) {
      asm volatile("s_waitcnt vmcnt(3)" ::: "memory");  // t+1 in flight
    } else {
      asm volatile("s_waitcnt vmcnt(0)" ::: "memory");
    }
    __builtin_amdgcn_s_barrier();

    bf16x8 af[4];
    #pragma unroll
    for (int mt = 0; mt < 4; ++mt)
      af[mt] = *(const bf16x8*)(&As[cur][(wm * 64 + mt * 16 + l15) * BK + fsw]);
    #pragma unroll
    for (int nt = 0; nt < 2; ++nt) {
      int col = wnq * 32 + nt * 16 + l15;
      bf16x8 bgf  = *(const bf16x8*)(&Bg[cur][col * BK + fsw]);
      bf16x8 buf_ = *(const bf16x8*)(&Bu[cur][col * BK + fsw]);
      #pragma unroll
      for (int mt = 0; mt < 4; ++mt) {
        accg[mt][nt] = __builtin_amdgcn_mfma_f32_16x16x32_bf16(af[mt], bgf,  accg[mt][nt], 0, 0, 0);
        accu[mt][nt] = __builtin_amdgcn_mfma_f32_16x16x32_bf16(af[mt], buf_, accu[mt][nt], 0, 0, 0);
      }
    }
    asm volatile("s_waitcnt lgkmcnt(0)" ::: "memory");  // frag reads done
    __builtin_amdgcn_s_barrier();   // buf cur reusable (restaged next iter)
    cur = (cur == 2) ? 0 : cur + 1;
  }

  int cc = l15, rg = q;
  #pragma unroll
  for (int mt = 0; mt < 4; ++mt) {
    #pragma unroll
    for (int r = 0; r < 4; ++r) {
      int pos = m0 + wm * 64 + mt * 16 + rg * 4 + r;
      if (pos >= nCnt) continue;
      int ak = list_ak[e * TT + pos];
      #pragma unroll
      for (int nt = 0; nt < 2; ++nt) {
        int ncol = c0 + wnq * 32 + nt * 16 + cc;
        float avl = gelu_t(accg[mt][nt][r]) * accu[mt][nt][r];
        act[(size_t)ak * ID + ncol] = (unsigned short)f2bf(avl);
      }
    }
  }
}

// ---------------- D GEMM: yw[ks] = w * (act @ WdT_e), split-K=2 ----------------
__global__ __launch_bounds__(512, 4) void d_gemm(
    const unsigned short* __restrict__ act,  // [T*2, I] bf16
    const unsigned short* __restrict__ wdT,  // [E][H][I] bf16 (transposed)
    float* __restrict__ yw,                  // [2][T*2, H] fp32 partials
    const int* __restrict__ counts, const int* __restrict__ list_ak,
    const float* __restrict__ wlist)
{
  int e = blockIdx.z;
  int nCnt = counts[e];
  int m0 = (blockIdx.y >> 1) * BM;
  int ks = blockIdx.y & 1;
  if (m0 >= nCnt) return;
  int c0 = blockIdx.x * 128;
  const unsigned short* Wd = wdT + (size_t)e * ID * HD;   // [H][I]

  __shared__ __align__(16) unsigned short As[3][BM * BK];    // 24 KB
  __shared__ __align__(16) unsigned short Bt[3][128 * BK];   // 24 KB

  int tid = threadIdx.x;
  int wave = tid >> 6, lane = tid & 63;
  int wm = wave >> 2, wnq = wave & 3;
  int q = lane >> 4, l15 = lane & 15;
  int usw = ((lane & 3) ^ ((lane >> 3) & 3)) * 8;
  int fsw = (q ^ ((l15 >> 1) & 3)) * 8;

  int srow = wave * 16 + (lane >> 2);
  int gpos = m0 + srow; if (gpos >= nCnt) gpos = nCnt - 1;
  const unsigned short* aptr =
      act + (size_t)list_ak[e * TT + gpos] * ID + ks * 1024 + usw;
  const unsigned short* bp =
      Wd + (size_t)(c0 + srow) * ID + ks * 1024 + usw;
  int so = wave * 512;

  // 2 glls per wave per tile
  auto stage = [&](int k0, int b) {
    gll16(aptr + k0, &As[b][so]);
    gll16(bp + k0,   &Bt[b][so]);
  };

  f32x4 acc[4][2];
  f32x4 zed = {0.f, 0.f, 0.f, 0.f};
  #pragma unroll
  for (int i = 0; i < 4; ++i)
    #pragma unroll
    for (int j = 0; j < 2; ++j) acc[i][j] = zed;

  stage(0, 0);
  stage(BK, 1);

  int cur = 0;
  for (int k0 = 0; k0 < 1024; k0 += BK) {
    int n2 = k0 + 2 * BK;
    if (n2 < 1024) {
      int b2 = cur + 2; if (b2 >= 3) b2 -= 3;
      stage(n2, b2);
      asm volatile("s_waitcnt vmcnt(4)" ::: "memory");
    } else if (k0 + BK < 1024) {
      asm volatile("s_waitcnt vmcnt(2)" ::: "memory");
    } else {
      asm volatile("s_waitcnt vmcnt(0)" ::: "memory");
    }
    __builtin_amdgcn_s_barrier();

    bf16x8 af[4], bf[2];
    #pragma unroll
    for (int mt = 0; mt < 4; ++mt)
      af[mt] = *(const bf16x8*)(&As[cur][(wm * 64 + mt * 16 + l15) * BK + fsw]);
    #pragma unroll
    for (int nt = 0; nt < 2; ++nt) {
      int col = wnq * 32 + nt * 16 + l15;
      bf[nt] = *(const bf16x8*)(&Bt[cur][col * BK + fsw]);
    }
    #pragma unroll
    for (int mt = 0; mt < 4; ++mt)
      #pragma unroll
      for (int nt = 0; nt < 2; ++nt)
        acc[mt][nt] = __builtin_amdgcn_mfma_f32_16x16x32_bf16(af[mt], bf[nt], acc[mt][nt], 0, 0, 0);

    asm volatile("s_waitcnt lgkmcnt(0)" ::: "memory");
    __builtin_amdgcn_s_barrier();
    cur = (cur == 2) ? 0 : cur + 1;
  }

  int cc = l15, rg = q;
  #pragma unroll
  for (int mt = 0; mt < 4; ++mt) {
    #pragma unroll
    for (int r = 0; r < 4; ++r) {
      int pos = m0 + wm * 64 + mt * 16 + rg * 4 + r;
      if (pos >= nCnt) continue;
      int ak = list_ak[e * TT + pos];
      float wsc = wlist[e * TT + pos];
      #pragma unroll
      for (int nt = 0; nt < 2; ++nt) {
        int ncol = c0 + wnq * 32 + nt * 16 + cc;
        yw[((size_t)ks * (TT * 2) + ak) * HD + ncol] = acc[mt][nt][r] * wsc;
      }
    }
  }
}

// ---------------- out[t,h] = sum over {2t,2t+1} x {ks0,ks1} ----------------
__global__ void combine_kernel(const float* __restrict__ yw, float* __restrict__ out)
{
  const int total = TT * HD / 4;
  const size_t S = (size_t)TT * 2 * HD;
  for (int i = blockIdx.x * blockDim.x + threadIdx.x; i < total;
       i += gridDim.x * blockDim.x) {
    int i4 = i * 4;
    int t = i4 >> 10;
    int h = i4 & (HD - 1);
    float4 a = *(const float4*)(yw + (size_t)(2 * t) * HD + h);
    float4 b = *(const float4*)(yw + (size_t)(2 * t + 1) * HD + h);
    float4 c = *(const float4*)(yw + S + (size_t)(2 * t) * HD + h);
    float4 d = *(const float4*)(yw + S + (size_t)(2 * t + 1) * HD + h);
    float4 o;
    o.x = a.x + b.x + c.x + d.x;
    o.y = a.y + b.y + c.y + d.y;
    o.z = a.z + b.z + c.z + d.z;
    o.w = a.w + b.w + c.w + d.w;
    *(float4*)(out + (size_t)i4) = o;
  }
}

extern "C" void kernel_launch(void* const* d_in, const int* in_sizes, int n_in,
                              void* d_out, int out_size, void* d_ws, size_t ws_size,
                              hipStream_t stream) {
  const float* x  = (const float*)d_in[0];
  const float* gw = (const float*)d_in[1];
  const float* wg = (const float*)d_in[2];
  const float* wu = (const float*)d_in[3];
  const float* wd = (const float*)d_in[4];
  float* out = (float*)d_out;

  // workspace layout (~156 MB total)
  char* ws = (char*)d_ws;
  int* counts   = (int*)ws;
  int* list_ak  = (int*)(ws + 256);
  float* wlist  = (float*)(ws + 256 + 65536);
  size_t off = 256 + 2 * 65536;
  unsigned short* xb  = (unsigned short*)(ws + off); off += (size_t)TT * HD * 2;        // 4 MB
  unsigned short* act = (unsigned short*)(ws + off); off += (size_t)TT * 2 * ID * 2;    // 16 MB
  float* yw           = (float*)(ws + off);          off += (size_t)2 * TT * 2 * HD * 4;// 33.5 MB
  unsigned short* wgT = (unsigned short*)(ws + off); off += (size_t)NE * HD * ID * 2;   // 33.5 MB
  unsigned short* wuT = (unsigned short*)(ws + off); off += (size_t)NE * HD * ID * 2;   // 33.5 MB
  unsigned short* wdT = (unsigned short*)(ws + off);                                    // 33.5 MB

  (void)hipMemsetAsync(counts, 0, 256, stream);
  router_kernel<<<TT, 64, 0, stream>>>(x, gw, counts, list_ak, wlist);
  xcvt_kernel<<<TT * HD / 8 / 256, 256, 0, stream>>>(x, xb);

  // weight convert+transpose: wg/wu [H][I] -> [I][H]; wd [I][H] -> [H][I]
  tcvt_kernel<<<dim3(ID / 64, HD / 64, NE), 256, 0, stream>>>(wg, wgT, HD, ID);
  tcvt_kernel<<<dim3(ID / 64, HD / 64, NE), 256, 0, stream>>>(wu, wuT, HD, ID);
  tcvt_kernel<<<dim3(HD / 64, ID / 64, NE), 256, 0, stream>>>(wd, wdT, ID, HD);

  dim3 blk(512);
  dim3 gGU(ID / 128, 16, NE);    // 16 m-slots x 128 rows covers nCnt<=2048
  gu_gemm<<<gGU, blk, 0, stream>>>(xb, wgT, wuT, act, counts, list_ak);

  dim3 gD(HD / 128, 32, NE);     // y = 16 m-slots x 2 k-slices
  d_gemm<<<gD, blk, 0, stream>>>(act, wdT, yw, counts, list_ak, wlist);

  combine_kernel<<<1024, 256, 0, stream>>>(yw, out);
}

// Round 7
// 374.061 us; speedup vs baseline: 1.0279x; 1.0279x over previous
//
#include <hip/hip_runtime.h>
#include <hip/hip_bf16.h>

#define TT 2048
#define HD 1024
#define NE 8
#define ID 2048

typedef short bf16x8 __attribute__((ext_vector_type(8)));
typedef float f32x4 __attribute__((ext_vector_type(4)));

__device__ __forceinline__ unsigned f2bf(float f){
  unsigned u = __float_as_uint(f);
  return (u + 0x7FFFu + ((u >> 16) & 1u)) >> 16;  // RNE
}
__device__ __forceinline__ float gelu_t(float x){
  float x3 = x * x * x;
  return 0.5f * x * (1.f + tanhf(0.7978845608028654f * (x + 0.044715f * x3)));
}

// async global->LDS, 16B per lane. LDS dest = wave-uniform base + lane*16;
// global source address is PER-LANE (swizzle lives on the source side).
typedef const __attribute__((address_space(1))) unsigned int as1_uint;
typedef __attribute__((address_space(3))) unsigned int as3_uint;
__device__ __forceinline__ void gll16(const unsigned short* g, unsigned short* l) {
  __builtin_amdgcn_global_load_lds((as1_uint*)g, (as3_uint*)l, 16, 0, 0);
}

// ---------------- Router ----------------
__global__ __launch_bounds__(64) void router_kernel(
    const float* __restrict__ x, const float* __restrict__ gw,
    int* __restrict__ counts, int* __restrict__ list_ak, float* __restrict__ wlist)
{
  int t = blockIdx.x;
  int lane = threadIdx.x;
  float acc[NE];
  #pragma unroll
  for (int e = 0; e < NE; ++e) acc[e] = 0.f;
  const float* xr = x + (size_t)t * HD;
  #pragma unroll
  for (int j = 0; j < HD / 64; ++j) {
    int h = j * 64 + lane;
    float xv = xr[h];
    float4 g0 = *(const float4*)(gw + (size_t)h * NE);
    float4 g1 = *(const float4*)(gw + (size_t)h * NE + 4);
    acc[0] += xv * g0.x; acc[1] += xv * g0.y;
    acc[2] += xv * g0.z; acc[3] += xv * g0.w;
    acc[4] += xv * g1.x; acc[5] += xv * g1.y;
    acc[6] += xv * g1.z; acc[7] += xv * g1.w;
  }
  #pragma unroll
  for (int e = 0; e < NE; ++e) {
    float v = acc[e];
    #pragma unroll
    for (int off = 32; off > 0; off >>= 1) v += __shfl_xor(v, off, 64);
    acc[e] = v;
  }
  if (lane == 0) {
    float lg[NE];
    #pragma unroll
    for (int e = 0; e < NE; ++e) lg[e] = tanhf(acc[e] * (1.0f / 30.0f));
    int i0 = 0;
    #pragma unroll
    for (int e = 1; e < NE; ++e) if (lg[e] > lg[i0]) i0 = e;
    int i1 = (i0 == 0) ? 1 : 0;
    #pragma unroll
    for (int e = 0; e < NE; ++e) if (e != i0 && lg[e] > lg[i1]) i1 = e;
    float e1 = __expf(lg[i1] - lg[i0]);
    float w0 = 1.f / (1.f + e1);
    float w1 = 1.f - w0;
    int p0 = atomicAdd(counts + i0, 1);
    list_ak[i0 * TT + p0] = t * 2;
    wlist[i0 * TT + p0] = w0;
    int p1 = atomicAdd(counts + i1, 1);
    list_ak[i1 * TT + p1] = t * 2 + 1;
    wlist[i1 * TT + p1] = w1;
  }
}

// ---------------- x fp32 -> bf16 ----------------
__global__ void xcvt_kernel(const float* __restrict__ x, unsigned short* __restrict__ xb)
{
  int i = blockIdx.x * blockDim.x + threadIdx.x;   // 8 elems each
  const float* p = x + (size_t)i * 8;
  float4 v0 = *(const float4*)p;
  float4 v1 = *(const float4*)(p + 4);
  uint4 o;
  o.x = f2bf(v0.x) | (f2bf(v0.y) << 16);
  o.y = f2bf(v0.z) | (f2bf(v0.w) << 16);
  o.z = f2bf(v1.x) | (f2bf(v1.y) << 16);
  o.w = f2bf(v1.z) | (f2bf(v1.w) << 16);
  *(uint4*)(xb + (size_t)i * 8) = o;
}

// ---------------- weight transpose+convert: in fp32 [R][C] -> out bf16 [C][R]
__global__ __launch_bounds__(256) void tcvt_kernel(
    const float* __restrict__ in, unsigned short* __restrict__ out, int R, int C)
{
  __shared__ float tile[64 * 66];
  int e = blockIdx.z;
  const float* inp = in + (size_t)e * R * C;
  unsigned short* outp = out + (size_t)e * R * C;
  int r0 = blockIdx.y * 64, c0 = blockIdx.x * 64;
  int tid = threadIdx.x;
  int lr = tid >> 4, lc = (tid & 15) * 4;
  #pragma unroll
  for (int i = 0; i < 4; ++i) {
    float4 v = *(const float4*)(inp + (size_t)(r0 + i * 16 + lr) * C + c0 + lc);
    float* tp = &tile[(i * 16 + lr) * 66 + lc];
    tp[0] = v.x; tp[1] = v.y; tp[2] = v.z; tp[3] = v.w;
  }
  __syncthreads();
  int oc = tid >> 2, os = (tid & 3) * 16;
  unsigned short* op = outp + (size_t)(c0 + oc) * R + r0 + os;
  uint4 o[2];
  unsigned* ow = (unsigned*)o;
  #pragma unroll
  for (int m = 0; m < 8; ++m) {
    float a = tile[(os + 2 * m) * 66 + oc];
    float b = tile[(os + 2 * m + 1) * 66 + oc];
    ow[m] = f2bf(a) | (f2bf(b) << 16);
  }
  *(uint4*)op = o[0];
  *(uint4*)(op + 8) = o[1];
}

#define BK 32
#define BM 128
#define MSLOT 6   // m-slots per panel; covers nCnt <= 768 (mean 512, sigma ~21)

// LDS: linear [rows][32 k] bf16 (64B rows), staged entirely by global_load_lds
// (per-lane gather on the GLOBAL side). 16B-unit XOR swizzle pre-applied to the
// global source k-chunk; frag reads apply the same XOR -> conflict-free.
// 3-stage counted-vmcnt pipeline (2 tiles in flight).
// Round-7: XCD panel co-scheduling. Dispatch round-robins id%8 -> XCD. The 6
// m-variant blocks of one B-panel p get ids (p/8)*48 + m*8 + (p%8): all
// congruent to p (mod 8) -> SAME XCD, consecutive slots -> lockstep K
// streaming -> B re-reads become L2 hits instead of L3 streams (R6 showed all
// staged traffic was L3-served at ~5 TB/s = the wall).

// ---------------- Fused G+U gathered GEMM, act epilogue ----------------
// 8 waves as 2m x 4n: wave computes 64m x 32n of both G and U.
__global__ __launch_bounds__(512, 4) void gu_gemm(
    const unsigned short* __restrict__ xb,   // [T,H] bf16
    const unsigned short* __restrict__ wgT,  // [E][I][H] bf16 (transposed)
    const unsigned short* __restrict__ wuT,
    unsigned short* __restrict__ act,        // [T*2, I] bf16
    const int* __restrict__ counts, const int* __restrict__ list_ak)
{
  // id -> (panel p, m-slot): p = (id/48)*8 + id%8 ; m = (id%48)/8
  int gid = blockIdx.x;
  int grp = gid / 48, w48 = gid % 48;
  int mslot = w48 >> 3;
  int p = grp * 8 + (w48 & 7);        // 0..127
  int e = p >> 4;                      // 8 experts
  int c0 = (p & 15) * 128;             // 16 c-panels
  int nCnt = counts[e];
  int m0 = mslot * BM;
  if (m0 >= nCnt) return;
  const unsigned short* Wg = wgT + (size_t)e * HD * ID;
  const unsigned short* Wu = wuT + (size_t)e * HD * ID;

  __shared__ __align__(16) unsigned short As[3][BM * BK];    // 24 KB
  __shared__ __align__(16) unsigned short Bg[3][128 * BK];   // 24 KB
  __shared__ __align__(16) unsigned short Bu[3][128 * BK];   // 24 KB

  int tid = threadIdx.x;
  int wave = tid >> 6, lane = tid & 63;      // 8 waves
  int wm = wave >> 2, wnq = wave & 3;        // 2m x 4n
  int q = lane >> 4, l15 = lane & 15;
  int usw = ((lane & 3) ^ ((lane >> 3) & 3)) * 8;  // source k-chunk (shorts)
  int fsw = (q ^ ((l15 >> 1) & 3)) * 8;            // frag-read swizzle

  // staging: wave w covers rows/cols w*16 .. w*16+15 (lane>>2), unit lane&3
  int srow = wave * 16 + (lane >> 2);
  int gpos = m0 + srow; if (gpos >= nCnt) gpos = nCnt - 1;   // clamp, row unused
  const unsigned short* aptr =
      xb + (size_t)(list_ak[e * TT + gpos] >> 1) * HD + usw;
  const unsigned short* bgp = Wg + (size_t)(c0 + srow) * HD + usw;
  const unsigned short* bup = Wu + (size_t)(c0 + srow) * HD + usw;
  int so = wave * 512;   // shorts: wave-uniform LDS base (16 rows * 32)

  // 3 glls per wave per tile
  auto stage = [&](int k0, int b) {
    gll16(aptr + k0, &As[b][so]);
    gll16(bgp + k0,  &Bg[b][so]);
    gll16(bup + k0,  &Bu[b][so]);
  };

  f32x4 accg[4][2], accu[4][2];
  f32x4 zed = {0.f, 0.f, 0.f, 0.f};
  #pragma unroll
  for (int i = 0; i < 4; ++i)
    #pragma unroll
    for (int j = 0; j < 2; ++j) { accg[i][j] = zed; accu[i][j] = zed; }

  stage(0, 0);
  stage(BK, 1);

  int cur = 0;
  for (int k0 = 0; k0 < HD; k0 += BK) {
    int n2 = k0 + 2 * BK;
    if (n2 < HD) {
      int b2 = cur + 2; if (b2 >= 3) b2 -= 3;
      stage(n2, b2);
      asm volatile("s_waitcnt vmcnt(6)" ::: "memory");  // t+1,t+2 in flight
    } else if (k0 + BK < HD) {
      asm volatile("s_waitcnt vmcnt(3)" ::: "memory");  // t+1 in flight
    } else {
      asm volatile("s_waitcnt vmcnt(0)" ::: "memory");
    }
    __builtin_amdgcn_s_barrier();

    bf16x8 af[4];
    #pragma unroll
    for (int mt = 0; mt < 4; ++mt)
      af[mt] = *(const bf16x8*)(&As[cur][(wm * 64 + mt * 16 + l15) * BK + fsw]);
    #pragma unroll
    for (int nt = 0; nt < 2; ++nt) {
      int col = wnq * 32 + nt * 16 + l15;
      bf16x8 bgf  = *(const bf16x8*)(&Bg[cur][col * BK + fsw]);
      bf16x8 buf_ = *(const bf16x8*)(&Bu[cur][col * BK + fsw]);
      #pragma unroll
      for (int mt = 0; mt < 4; ++mt) {
        accg[mt][nt] = __builtin_amdgcn_mfma_f32_16x16x32_bf16(af[mt], bgf,  accg[mt][nt], 0, 0, 0);
        accu[mt][nt] = __builtin_amdgcn_mfma_f32_16x16x32_bf16(af[mt], buf_, accu[mt][nt], 0, 0, 0);
      }
    }
    asm volatile("s_waitcnt lgkmcnt(0)" ::: "memory");  // frag reads done
    __builtin_amdgcn_s_barrier();   // buf cur reusable (restaged next iter)
    cur = (cur == 2) ? 0 : cur + 1;
  }

  int cc = l15, rg = q;
  #pragma unroll
  for (int mt = 0; mt < 4; ++mt) {
    #pragma unroll
    for (int r = 0; r < 4; ++r) {
      int pos = m0 + wm * 64 + mt * 16 + rg * 4 + r;
      if (pos >= nCnt) continue;
      int ak = list_ak[e * TT + pos];
      #pragma unroll
      for (int nt = 0; nt < 2; ++nt) {
        int ncol = c0 + wnq * 32 + nt * 16 + cc;
        float avl = gelu_t(accg[mt][nt][r]) * accu[mt][nt][r];
        act[(size_t)ak * ID + ncol] = (unsigned short)f2bf(avl);
      }
    }
  }
}

// ---------------- D GEMM: yw[ks] = w * (act @ WdT_e), split-K=2 ----------------
__global__ __launch_bounds__(512, 4) void d_gemm(
    const unsigned short* __restrict__ act,  // [T*2, I] bf16
    const unsigned short* __restrict__ wdT,  // [E][H][I] bf16 (transposed)
    float* __restrict__ yw,                  // [2][T*2, H] fp32 partials
    const int* __restrict__ counts, const int* __restrict__ list_ak,
    const float* __restrict__ wlist)
{
  // id -> (panel p, m-slot): p = (e,c,ks) 0..127
  int gid = blockIdx.x;
  int grp = gid / 48, w48 = gid % 48;
  int mslot = w48 >> 3;
  int p = grp * 8 + (w48 & 7);
  int e = p >> 4;                       // 8 experts
  int c0 = ((p >> 1) & 7) * 128;        // 8 c-panels
  int ks = p & 1;                       // 2 k-slices
  int nCnt = counts[e];
  int m0 = mslot * BM;
  if (m0 >= nCnt) return;
  const unsigned short* Wd = wdT + (size_t)e * ID * HD;   // [H][I]

  __shared__ __align__(16) unsigned short As[3][BM * BK];    // 24 KB
  __shared__ __align__(16) unsigned short Bt[3][128 * BK];   // 24 KB

  int tid = threadIdx.x;
  int wave = tid >> 6, lane = tid & 63;
  int wm = wave >> 2, wnq = wave & 3;
  int q = lane >> 4, l15 = lane & 15;
  int usw = ((lane & 3) ^ ((lane >> 3) & 3)) * 8;
  int fsw = (q ^ ((l15 >> 1) & 3)) * 8;

  int srow = wave * 16 + (lane >> 2);
  int gpos = m0 + srow; if (gpos >= nCnt) gpos = nCnt - 1;
  const unsigned short* aptr =
      act + (size_t)list_ak[e * TT + gpos] * ID + ks * 1024 + usw;
  const unsigned short* bp =
      Wd + (size_t)(c0 + srow) * ID + ks * 1024 + usw;
  int so = wave * 512;

  // 2 glls per wave per tile
  auto stage = [&](int k0, int b) {
    gll16(aptr + k0, &As[b][so]);
    gll16(bp + k0,   &Bt[b][so]);
  };

  f32x4 acc[4][2];
  f32x4 zed = {0.f, 0.f, 0.f, 0.f};
  #pragma unroll
  for (int i = 0; i < 4; ++i)
    #pragma unroll
    for (int j = 0; j < 2; ++j) acc[i][j] = zed;

  stage(0, 0);
  stage(BK, 1);

  int cur = 0;
  for (int k0 = 0; k0 < 1024; k0 += BK) {
    int n2 = k0 + 2 * BK;
    if (n2 < 1024) {
      int b2 = cur + 2; if (b2 >= 3) b2 -= 3;
      stage(n2, b2);
      asm volatile("s_waitcnt vmcnt(4)" ::: "memory");
    } else if (k0 + BK < 1024) {
      asm volatile("s_waitcnt vmcnt(2)" ::: "memory");
    } else {
      asm volatile("s_waitcnt vmcnt(0)" ::: "memory");
    }
    __builtin_amdgcn_s_barrier();

    bf16x8 af[4], bf[2];
    #pragma unroll
    for (int mt = 0; mt < 4; ++mt)
      af[mt] = *(const bf16x8*)(&As[cur][(wm * 64 + mt * 16 + l15) * BK + fsw]);
    #pragma unroll
    for (int nt = 0; nt < 2; ++nt) {
      int col = wnq * 32 + nt * 16 + l15;
      bf[nt] = *(const bf16x8*)(&Bt[cur][col * BK + fsw]);
    }
    #pragma unroll
    for (int mt = 0; mt < 4; ++mt)
      #pragma unroll
      for (int nt = 0; nt < 2; ++nt)
        acc[mt][nt] = __builtin_amdgcn_mfma_f32_16x16x32_bf16(af[mt], bf[nt], acc[mt][nt], 0, 0, 0);

    asm volatile("s_waitcnt lgkmcnt(0)" ::: "memory");
    __builtin_amdgcn_s_barrier();
    cur = (cur == 2) ? 0 : cur + 1;
  }

  int cc = l15, rg = q;
  #pragma unroll
  for (int mt = 0; mt < 4; ++mt) {
    #pragma unroll
    for (int r = 0; r < 4; ++r) {
      int pos = m0 + wm * 64 + mt * 16 + rg * 4 + r;
      if (pos >= nCnt) continue;
      int ak = list_ak[e * TT + pos];
      float wsc = wlist[e * TT + pos];
      #pragma unroll
      for (int nt = 0; nt < 2; ++nt) {
        int ncol = c0 + wnq * 32 + nt * 16 + cc;
        yw[((size_t)ks * (TT * 2) + ak) * HD + ncol] = acc[mt][nt][r] * wsc;
      }
    }
  }
}

// ---------------- out[t,h] = sum over {2t,2t+1} x {ks0,ks1} ----------------
__global__ void combine_kernel(const float* __restrict__ yw, float* __restrict__ out)
{
  const int total = TT * HD / 4;
  const size_t S = (size_t)TT * 2 * HD;
  for (int i = blockIdx.x * blockDim.x + threadIdx.x; i < total;
       i += gridDim.x * blockDim.x) {
    int i4 = i * 4;
    int t = i4 >> 10;
    int h = i4 & (HD - 1);
    float4 a = *(const float4*)(yw + (size_t)(2 * t) * HD + h);
    float4 b = *(const float4*)(yw + (size_t)(2 * t + 1) * HD + h);
    float4 c = *(const float4*)(yw + S + (size_t)(2 * t) * HD + h);
    float4 d = *(const float4*)(yw + S + (size_t)(2 * t + 1) * HD + h);
    float4 o;
    o.x = a.x + b.x + c.x + d.x;
    o.y = a.y + b.y + c.y + d.y;
    o.z = a.z + b.z + c.z + d.z;
    o.w = a.w + b.w + c.w + d.w;
    *(float4*)(out + (size_t)i4) = o;
  }
}

extern "C" void kernel_launch(void* const* d_in, const int* in_sizes, int n_in,
                              void* d_out, int out_size, void* d_ws, size_t ws_size,
                              hipStream_t stream) {
  const float* x  = (const float*)d_in[0];
  const float* gw = (const float*)d_in[1];
  const float* wg = (const float*)d_in[2];
  const float* wu = (const float*)d_in[3];
  const float* wd = (const float*)d_in[4];
  float* out = (float*)d_out;

  // workspace layout (~156 MB total)
  char* ws = (char*)d_ws;
  int* counts   = (int*)ws;
  int* list_ak  = (int*)(ws + 256);
  float* wlist  = (float*)(ws + 256 + 65536);
  size_t off = 256 + 2 * 65536;
  unsigned short* xb  = (unsigned short*)(ws + off); off += (size_t)TT * HD * 2;        // 4 MB
  unsigned short* act = (unsigned short*)(ws + off); off += (size_t)TT * 2 * ID * 2;    // 16 MB
  float* yw           = (float*)(ws + off);          off += (size_t)2 * TT * 2 * HD * 4;// 33.5 MB
  unsigned short* wgT = (unsigned short*)(ws + off); off += (size_t)NE * HD * ID * 2;   // 33.5 MB
  unsigned short* wuT = (unsigned short*)(ws + off); off += (size_t)NE * HD * ID * 2;   // 33.5 MB
  unsigned short* wdT = (unsigned short*)(ws + off);                                    // 33.5 MB

  (void)hipMemsetAsync(counts, 0, 256, stream);
  router_kernel<<<TT, 64, 0, stream>>>(x, gw, counts, list_ak, wlist);
  xcvt_kernel<<<TT * HD / 8 / 256, 256, 0, stream>>>(x, xb);

  // weight convert+transpose: wg/wu [H][I] -> [I][H]; wd [I][H] -> [H][I]
  tcvt_kernel<<<dim3(ID / 64, HD / 64, NE), 256, 0, stream>>>(wg, wgT, HD, ID);
  tcvt_kernel<<<dim3(ID / 64, HD / 64, NE), 256, 0, stream>>>(wu, wuT, HD, ID);
  tcvt_kernel<<<dim3(HD / 64, ID / 64, NE), 256, 0, stream>>>(wd, wdT, ID, HD);

  dim3 blk(512);
  // 1D XCD-panel-swizzled grids: 128 panels x 6 m-slots = 768 blocks each
  gu_gemm<<<128 * MSLOT, blk, 0, stream>>>(xb, wgT, wuT, act, counts, list_ak);
  d_gemm<<<128 * MSLOT, blk, 0, stream>>>(act, wdT, yw, counts, list_ak, wlist);

  combine_kernel<<<1024, 256, 0, stream>>>(yw, out);
}